// Round 4
// baseline (421.158 us; speedup 1.0000x reference)
//
#include <hip/hip_runtime.h>
#include <hip/hip_bf16.h>

// CrossAttention: B=4, Tv=8192, Tt=77, C=1024, H=16, D=64
// q = video@Wq.T ; k,v = text@W{k,v}.T ; softmax(qk^T/8)v ; out = attn@Wo.T
// Round 3: attention fused into q-GEMM epilogue (128 rows x 2 heads per block).

typedef __attribute__((ext_vector_type(8))) short bf16x8;
typedef __attribute__((ext_vector_type(4))) float f32x4;
typedef __attribute__((ext_vector_type(8))) unsigned short u16x8;
typedef __attribute__((ext_vector_type(4))) unsigned short u16x4;

typedef const __attribute__((address_space(1))) void gv_t;
typedef __attribute__((address_space(3))) void lv_t;

static __device__ __forceinline__ unsigned short f2bf(float f) {
    union { float f; unsigned u; } v; v.f = f;
    unsigned r = v.u + 0x7FFFu + ((v.u >> 16) & 1u);  // RNE
    return (unsigned short)(r >> 16);
}

constexpr int Bn = 4, TVn = 8192, TTn = 77, Cn = 1024, Hn = 16;

// ---------------- fp32 -> bf16 convert, 8 elems/thread ----------------
__global__ void k_cvt8(const float* __restrict__ in, unsigned short* __restrict__ out, int n8) {
    int i = blockIdx.x * 256 + threadIdx.x;
    if (i >= n8) return;
    const float4* p = reinterpret_cast<const float4*>(in) + (size_t)i * 2;
    float4 a = p[0], b = p[1];
    u16x8 o = { f2bf(a.x), f2bf(a.y), f2bf(a.z), f2bf(a.w),
                f2bf(b.x), f2bf(b.y), f2bf(b.z), f2bf(b.w) };
    *reinterpret_cast<u16x8*>(out + (size_t)i * 8) = o;
}

// ---------------- fused: q = video@Wq.T (128x128 tile) then attention for the 2 heads ----------------
__global__ __launch_bounds__(256)
void k_gemm_qattn(const unsigned short* __restrict__ A,   // video bf16 [32768][1024]
                  const unsigned short* __restrict__ Wb,  // Wq bf16 [1024][1024]
                  const unsigned short* __restrict__ kb,  // k bf16 [B*77][1024]
                  const unsigned short* __restrict__ vb,  // v bf16 [B*77][1024]
                  unsigned short* __restrict__ outp) {    // attn bf16 [32768][1024]
    constexpr int QLP = 72, KP = 72, VP = 104, PP = 104;
    // phase-2 layout (u16 offsets): q_lds[128][72] | k_s[80][72] | vt_s[64][104] | p_s[128][104]
    __shared__ unsigned short smem[9216 + 5760 + 6656 + 13312];  // 69888 B
    unsigned short* q_lds = smem;
    unsigned short* k_s  = smem + 9216;
    unsigned short* vt_s = smem + 9216 + 5760;
    unsigned short* p_s  = smem + 9216 + 5760 + 6656;
    unsigned short* As = smem;          // [128][32], aliases q_lds during K-loop
    unsigned short* Bs = smem + 4096;

    const int tid = threadIdx.x, lane = tid & 63, wv = tid >> 6;
    const int orig = blockIdx.x;
    const int work = (orig & 7) * 256 + (orig >> 3);   // bijective XCD swizzle (2048 % 8 == 0)
    const int m0 = (work >> 3) * 128, n0 = (work & 7) * 128;
    const int wr = (wv >> 1) * 64, wc = (wv & 1) * 64;
    const int lr = lane & 15, lg = lane >> 4;
    const int brow = lane >> 2, bseg = lane & 3;

    f32x4 acc[4][4] = {};
    for (int kk = 0; kk < 1024; kk += 32) {
        #pragma unroll
        for (int j = 0; j < 2; ++j) {
            int chunk = wv * 2 + j;                  // 16 rows x 32 cols per 1 KiB chunk
            int trow = chunk * 16 + brow;
            int sseg = bseg ^ ((trow >> 1) & 3);     // pre-swizzled global source segment
            const unsigned short* ga = A + (size_t)(m0 + trow) * 1024 + kk + sseg * 8;
            __builtin_amdgcn_global_load_lds((gv_t*)ga, (lv_t*)&As[chunk * 512], 16, 0, 0);
            const unsigned short* gb = Wb + (size_t)(n0 + trow) * 1024 + kk + sseg * 8;
            __builtin_amdgcn_global_load_lds((gv_t*)gb, (lv_t*)&Bs[chunk * 512], 16, 0, 0);
        }
        __syncthreads();
        bf16x8 af[4], bfv[4];
        #pragma unroll
        for (int m = 0; m < 4; ++m) {
            int R = wr + m * 16 + lr;
            int seg = lg ^ ((R >> 1) & 3);           // matching read-side swizzle
            af[m] = *reinterpret_cast<const bf16x8*>(&As[R * 32 + seg * 8]);
        }
        #pragma unroll
        for (int n = 0; n < 4; ++n) {
            int R = wc + n * 16 + lr;
            int seg = lg ^ ((R >> 1) & 3);
            bfv[n] = *reinterpret_cast<const bf16x8*>(&Bs[R * 32 + seg * 8]);
        }
        #pragma unroll
        for (int m = 0; m < 4; ++m)
            #pragma unroll
            for (int n = 0; n < 4; ++n)
                acc[m][n] = __builtin_amdgcn_mfma_f32_16x16x32_bf16(af[m], bfv[n], acc[m][n], 0, 0, 0);
        __syncthreads();
    }

    // ---- attention epilogue: two heads (cols n0..n0+63 and n0+64..n0+127) ----
    const int b = m0 >> 13;              // rows of one tile stay within one batch (8192 % 128 == 0)
    for (int hl = 0; hl < 2; ++hl) {
        const int h = (n0 >> 6) + hl;
        const size_t kvbase = (size_t)b * TTn * Cn + h * 64;
        __syncthreads();  // previous phase (K-loop / previous head's PV+QK^T LDS reads) done

        // q tile -> LDS (bf16): only waves owning this head's columns
        if ((wv & 1) == hl) {
            #pragma unroll
            for (int m = 0; m < 4; ++m)
                #pragma unroll
                for (int n = 0; n < 4; ++n)
                    #pragma unroll
                    for (int r = 0; r < 4; ++r) {
                        unsigned short bv = f2bf(acc[m][n][r]);
                        unsigned ov = __shfl_xor((unsigned)bv, 1);
                        if (!(lane & 1)) {
                            int row = wr + m * 16 + lg * 4 + r;
                            int col = n * 16 + lr;   // head-local d
                            *reinterpret_cast<unsigned*>(&q_lds[row * QLP + col]) =
                                (unsigned)bv | (ov << 16);
                        }
                    }
        }
        // stage K (80 rows, 3 zero) and V^T (64 x 104, cols >=77 zero)
        for (int li = tid; li < 640; li += 256) {
            int t = li >> 3, c8 = (li & 7) * 8;
            u16x8 v = {0, 0, 0, 0, 0, 0, 0, 0};
            if (t < 77) v = *reinterpret_cast<const u16x8*>(kb + kvbase + (size_t)t * Cn + c8);
            *reinterpret_cast<u16x8*>(&k_s[t * KP + c8]) = v;
        }
        for (int li = tid; li < 80 * 64; li += 256) {
            int t = li >> 6, d = li & 63;
            unsigned short v = 0;
            if (t < 77) v = vb[kvbase + (size_t)t * Cn + d];
            vt_s[d * VP + t] = v;
        }
        for (int li = tid; li < 64 * 16; li += 256) {
            int d = li >> 4, t = 80 + (li & 15);
            vt_s[d * VP + t] = 0;
        }
        __syncthreads();

        // QK^T: rows wv*32..+32 per wave
        f32x4 sc[2][5] = {};
        #pragma unroll
        for (int ks = 0; ks < 2; ++ks) {
            bf16x8 qa[2], kf[5];
            #pragma unroll
            for (int mf = 0; mf < 2; ++mf)
                qa[mf] = *reinterpret_cast<const bf16x8*>(
                    &q_lds[(wv * 32 + mf * 16 + lr) * QLP + ks * 32 + (lg * 8)]);
            #pragma unroll
            for (int nf = 0; nf < 5; ++nf)
                kf[nf] = *reinterpret_cast<const bf16x8*>(
                    &k_s[(nf * 16 + lr) * KP + ks * 32 + (lg * 8)]);
            #pragma unroll
            for (int mf = 0; mf < 2; ++mf)
                #pragma unroll
                for (int nf = 0; nf < 5; ++nf)
                    sc[mf][nf] = __builtin_amdgcn_mfma_f32_16x16x32_bf16(qa[mf], kf[nf], sc[mf][nf], 0, 0, 0);
        }
        // softmax over 77 keys (C-layout: row=(lane>>4)*4+r, col t = nf*16+(lane&15))
        float pr[2][5][4];
        float rs[2][4];
        #pragma unroll
        for (int mf = 0; mf < 2; ++mf) {
            #pragma unroll
            for (int r = 0; r < 4; ++r) {
                float mx = -1e30f;
                #pragma unroll
                for (int nf = 0; nf < 5; ++nf) {
                    float s = sc[mf][nf][r];
                    if (nf * 16 + lr >= 77) s = -1e30f;
                    pr[mf][nf][r] = s;
                    mx = fmaxf(mx, s);
                }
                #pragma unroll
                for (int x = 1; x < 16; x <<= 1) mx = fmaxf(mx, __shfl_xor(mx, x));
                float sum = 0.f;
                #pragma unroll
                for (int nf = 0; nf < 5; ++nf) {
                    float p = (pr[mf][nf][r] > -1e29f) ? __expf((pr[mf][nf][r] - mx) * 0.125f) : 0.f;
                    pr[mf][nf][r] = p;
                    sum += p;
                }
                #pragma unroll
                for (int x = 1; x < 16; x <<= 1) sum += __shfl_xor(sum, x);
                rs[mf][r] = 1.f / sum;
            }
        }
        // P -> LDS. Each wave writes AND reads only its own 32 rows: no barrier needed.
        for (int li = lane; li < 512; li += 64) {
            int rr = wv * 32 + (li >> 4);
            p_s[rr * PP + 80 + (li & 15)] = 0;
        }
        #pragma unroll
        for (int mf = 0; mf < 2; ++mf)
            #pragma unroll
            for (int r = 0; r < 4; ++r)
                #pragma unroll
                for (int nf = 0; nf < 5; ++nf)
                    p_s[(wv * 32 + mf * 16 + lg * 4 + r) * PP + nf * 16 + lr] = f2bf(pr[mf][nf][r]);

        // PV
        f32x4 ovv[2][4] = {};
        #pragma unroll
        for (int ks = 0; ks < 3; ++ks) {
            bf16x8 pa[2], vf[4];
            #pragma unroll
            for (int mf = 0; mf < 2; ++mf)
                pa[mf] = *reinterpret_cast<const bf16x8*>(
                    &p_s[(wv * 32 + mf * 16 + lr) * PP + ks * 32 + (lg * 8)]);
            #pragma unroll
            for (int nf = 0; nf < 4; ++nf)
                vf[nf] = *reinterpret_cast<const bf16x8*>(
                    &vt_s[(nf * 16 + lr) * VP + ks * 32 + (lg * 8)]);
            #pragma unroll
            for (int mf = 0; mf < 2; ++mf)
                #pragma unroll
                for (int nf = 0; nf < 4; ++nf)
                    ovv[mf][nf] = __builtin_amdgcn_mfma_f32_16x16x32_bf16(pa[mf], vf[nf], ovv[mf][nf], 0, 0, 0);
        }
        #pragma unroll
        for (int mf = 0; mf < 2; ++mf)
            #pragma unroll
            for (int nf = 0; nf < 4; ++nf)
                #pragma unroll
                for (int r = 0; r < 4; ++r) {
                    float v = ovv[mf][nf][r] * rs[mf][r];
                    unsigned short bv = f2bf(v);
                    unsigned o = __shfl_xor((unsigned)bv, 1);
                    if (!(lane & 1)) {
                        int row = m0 + wv * 32 + mf * 16 + lg * 4 + r;
                        int col = n0 + hl * 64 + nf * 16 + lr;
                        *reinterpret_cast<unsigned*>(outp + (size_t)row * Cn + col) =
                            (unsigned)bv | (o << 16);
                    }
                }
    }
}

// ---------------- unified bf16 GEMM: A[32768][1024] @ W[1024][1024]^T, 128x128 tiles ----------------
template<int OUT_BF16>
__global__ __launch_bounds__(256)
void k_gemm_bb(const unsigned short* __restrict__ A, const unsigned short* __restrict__ Wb,
               void* __restrict__ outp) {
    __shared__ unsigned short As[128 * 32];
    __shared__ unsigned short Bs[128 * 32];
    const int tid = threadIdx.x, lane = tid & 63, wv = tid >> 6;
    const int orig = blockIdx.x;
    const int work = (orig & 7) * 256 + (orig >> 3);
    const int m0 = (work >> 3) * 128, n0 = (work & 7) * 128;
    const int wr = (wv >> 1) * 64, wc = (wv & 1) * 64;
    const int lr = lane & 15, lg = lane >> 4;
    const int brow = lane >> 2, bseg = lane & 3;
    f32x4 acc[4][4] = {};
    for (int kk = 0; kk < 1024; kk += 32) {
        #pragma unroll
        for (int j = 0; j < 2; ++j) {
            int chunk = wv * 2 + j;
            int trow = chunk * 16 + brow;
            int sseg = bseg ^ ((trow >> 1) & 3);
            const unsigned short* ga = A + (size_t)(m0 + trow) * 1024 + kk + sseg * 8;
            __builtin_amdgcn_global_load_lds((gv_t*)ga, (lv_t*)&As[chunk * 512], 16, 0, 0);
            const unsigned short* gb = Wb + (size_t)(n0 + trow) * 1024 + kk + sseg * 8;
            __builtin_amdgcn_global_load_lds((gv_t*)gb, (lv_t*)&Bs[chunk * 512], 16, 0, 0);
        }
        __syncthreads();
        bf16x8 af[4], bfv[4];
        #pragma unroll
        for (int m = 0; m < 4; ++m) {
            int R = wr + m * 16 + lr;
            int seg = lg ^ ((R >> 1) & 3);
            af[m] = *reinterpret_cast<const bf16x8*>(&As[R * 32 + seg * 8]);
        }
        #pragma unroll
        for (int n = 0; n < 4; ++n) {
            int R = wc + n * 16 + lr;
            int seg = lg ^ ((R >> 1) & 3);
            bfv[n] = *reinterpret_cast<const bf16x8*>(&Bs[R * 32 + seg * 8]);
        }
        #pragma unroll
        for (int m = 0; m < 4; ++m)
            #pragma unroll
            for (int n = 0; n < 4; ++n)
                acc[m][n] = __builtin_amdgcn_mfma_f32_16x16x32_bf16(af[m], bfv[n], acc[m][n], 0, 0, 0);
        __syncthreads();
    }
    #pragma unroll
    for (int m = 0; m < 4; ++m)
        #pragma unroll
        for (int n = 0; n < 4; ++n)
            #pragma unroll
            for (int r = 0; r < 4; ++r) {
                int grow = m0 + wr + m * 16 + lg * 4 + r;
                int gcol = n0 + wc + n * 16 + lr;
                if (OUT_BF16) {
                    unsigned short bv = f2bf(acc[m][n][r]);
                    unsigned ov = __shfl_xor((unsigned)bv, 1);
                    if (!(lane & 1)) {
                        unsigned short* out = (unsigned short*)outp;
                        *reinterpret_cast<unsigned*>(out + (size_t)grow * 1024 + gcol) =
                            (unsigned)bv | (ov << 16);
                    }
                } else {
                    float v = acc[m][n][r];
                    float o = __shfl_xor(v, 1);
                    if (!(lane & 1)) {
                        float* out = (float*)outp;
                        float2 pv; pv.x = v; pv.y = o;
                        *reinterpret_cast<float2*>(out + (size_t)grow * 1024 + gcol) = pv;
                    }
                }
            }
}

// ---------------- K/V projection: A fp32 [M][1024] @ W fp32 [1024][1024]^T -> bf16 ----------------
__global__ __launch_bounds__(256)
void k_gemm_kv(const float* __restrict__ A, const float* __restrict__ W0,
               const float* __restrict__ W1, unsigned short* __restrict__ o0,
               unsigned short* __restrict__ o1, int M) {
    const float* W = blockIdx.z ? W1 : W0;
    unsigned short* out = blockIdx.z ? o1 : o0;
    __shared__ unsigned short As[128 * 32];
    __shared__ unsigned short Bs[128 * 32];
    const int tid = threadIdx.x, lane = tid & 63, wv = tid >> 6;
    const int m0 = blockIdx.x * 128, n0 = blockIdx.y * 128;
    const int wr = (wv >> 1) * 64, wc = (wv & 1) * 64;
    const int lr = lane & 15, lk = (lane >> 4) * 8, lg = lane >> 4;
    f32x4 acc[4][4] = {};
    for (int kk = 0; kk < 1024; kk += 32) {
        #pragma unroll
        for (int it = 0; it < 4; ++it) {
            int li = it * 256 + tid;
            int row = li >> 3, c4 = (li & 7) * 4;
            int gr = m0 + row;
            float4 v = make_float4(0.f, 0.f, 0.f, 0.f);
            if (gr < M) v = *reinterpret_cast<const float4*>(A + (size_t)gr * 1024 + kk + c4);
            u16x4 o = { f2bf(v.x), f2bf(v.y), f2bf(v.z), f2bf(v.w) };
            *reinterpret_cast<u16x4*>(&As[row * 32 + c4]) = o;
        }
        #pragma unroll
        for (int it = 0; it < 4; ++it) {
            int li = it * 256 + tid;
            int row = li >> 3, c4 = (li & 7) * 4;
            float4 v = *reinterpret_cast<const float4*>(W + (size_t)(n0 + row) * 1024 + kk + c4);
            u16x4 o = { f2bf(v.x), f2bf(v.y), f2bf(v.z), f2bf(v.w) };
            *reinterpret_cast<u16x4*>(&Bs[row * 32 + c4]) = o;
        }
        __syncthreads();
        bf16x8 af[4], bfv[4];
        #pragma unroll
        for (int m = 0; m < 4; ++m)
            af[m] = *reinterpret_cast<const bf16x8*>(&As[(wr + m * 16 + lr) * 32 + lk]);
        #pragma unroll
        for (int n = 0; n < 4; ++n)
            bfv[n] = *reinterpret_cast<const bf16x8*>(&Bs[(wc + n * 16 + lr) * 32 + lk]);
        #pragma unroll
        for (int m = 0; m < 4; ++m)
            #pragma unroll
            for (int n = 0; n < 4; ++n)
                acc[m][n] = __builtin_amdgcn_mfma_f32_16x16x32_bf16(af[m], bfv[n], acc[m][n], 0, 0, 0);
        __syncthreads();
    }
    #pragma unroll
    for (int m = 0; m < 4; ++m)
        #pragma unroll
        for (int n = 0; n < 4; ++n)
            #pragma unroll
            for (int r = 0; r < 4; ++r) {
                int grow = m0 + wr + m * 16 + lg * 4 + r;
                if (grow < M) {
                    int gcol = n0 + wc + n * 16 + lr;
                    out[(size_t)grow * 1024 + gcol] = f2bf(acc[m][n][r]);
                }
            }
}

extern "C" void kernel_launch(void* const* d_in, const int* in_sizes, int n_in,
                              void* d_out, int out_size, void* d_ws, size_t ws_size,
                              hipStream_t stream) {
    const float* video = (const float*)d_in[0];
    const float* text  = (const float*)d_in[1];
    const float* Wq = (const float*)d_in[2];
    const float* Wk = (const float*)d_in[3];
    const float* Wv = (const float*)d_in[4];
    const float* Wo = (const float*)d_in[5];
    float* out = (float*)d_out;

    char* ws = (char*)d_ws;
    unsigned short* wq_b = (unsigned short*)(ws);                    // 2 MiB
    unsigned short* wo_b = (unsigned short*)(ws + (2u << 20));       // 2 MiB
    unsigned short* kbuf = (unsigned short*)(ws + (4u << 20));       // 616 KiB
    unsigned short* vbuf = (unsigned short*)(ws + (5u << 20));       // 616 KiB
    unsigned short* abuf = (unsigned short*)(ws + (6u << 20));       // 64 MiB attn output bf16
    unsigned short* vid_b = (unsigned short*)(ws + (70u << 20));     // 64 MiB video bf16

    k_cvt8<<<512, 256, 0, stream>>>(Wq, wq_b, 131072);
    k_cvt8<<<512, 256, 0, stream>>>(Wo, wo_b, 131072);

    dim3 gkv(3, 8, 2);  // ceil(308/128) x 1024/128 x {K,V}
    k_gemm_kv<<<gkv, 256, 0, stream>>>(text, Wk, Wv, kbuf, vbuf, Bn * TTn);

    k_cvt8<<<16384, 256, 0, stream>>>(video, vid_b, 4194304);

    k_gemm_qattn<<<2048, 256, 0, stream>>>(vid_b, wq_b, kbuf, vbuf, abuf);

    k_gemm_bb<0><<<2048, 256, 0, stream>>>(abuf, wo_b, (void*)out);
}

// Round 5
// 393.519 us; speedup vs baseline: 1.0702x; 1.0702x over previous
//
#include <hip/hip_runtime.h>
#include <hip/hip_bf16.h>

// CrossAttention: B=4, Tv=8192, Tt=77, C=1024, H=16, D=64
// q = video@Wq.T ; k,v = text@W{k,v}.T ; softmax(qk^T/8)v ; out = attn@Wo.T
// Round 4: revert fusion; low-latency attn (direct global frags, 1 barrier, 40KB LDS).

typedef __attribute__((ext_vector_type(8))) short bf16x8;
typedef __attribute__((ext_vector_type(4))) float f32x4;
typedef __attribute__((ext_vector_type(8))) unsigned short u16x8;
typedef __attribute__((ext_vector_type(4))) unsigned short u16x4;

typedef const __attribute__((address_space(1))) void gv_t;
typedef __attribute__((address_space(3))) void lv_t;

static __device__ __forceinline__ unsigned short f2bf(float f) {
    union { float f; unsigned u; } v; v.f = f;
    unsigned r = v.u + 0x7FFFu + ((v.u >> 16) & 1u);  // RNE
    return (unsigned short)(r >> 16);
}

constexpr int Bn = 4, TVn = 8192, TTn = 77, Cn = 1024, Hn = 16;

// ---------------- fp32 -> bf16 convert, 8 elems/thread ----------------
__global__ void k_cvt8(const float* __restrict__ in, unsigned short* __restrict__ out, int n8) {
    int i = blockIdx.x * 256 + threadIdx.x;
    if (i >= n8) return;
    const float4* p = reinterpret_cast<const float4*>(in) + (size_t)i * 2;
    float4 a = p[0], b = p[1];
    u16x8 o = { f2bf(a.x), f2bf(a.y), f2bf(a.z), f2bf(a.w),
                f2bf(b.x), f2bf(b.y), f2bf(b.z), f2bf(b.w) };
    *reinterpret_cast<u16x8*>(out + (size_t)i * 8) = o;
}

// ---------------- unified bf16 GEMM: A[32768][1024] @ W[1024][1024]^T, 128x128 tiles ----------------
// XCD-swizzled flat grid (2048 blocks), N fastest; both-sides LDS segment swizzle. (round-2 proven)
template<int OUT_BF16>
__global__ __launch_bounds__(256)
void k_gemm_bb(const unsigned short* __restrict__ A, const unsigned short* __restrict__ Wb,
               void* __restrict__ outp) {
    __shared__ unsigned short As[128 * 32];
    __shared__ unsigned short Bs[128 * 32];
    const int tid = threadIdx.x, lane = tid & 63, wv = tid >> 6;
    const int orig = blockIdx.x;
    const int work = (orig & 7) * 256 + (orig >> 3);   // bijective XCD swizzle (2048 % 8 == 0)
    const int m0 = (work >> 3) * 128, n0 = (work & 7) * 128;
    const int wr = (wv >> 1) * 64, wc = (wv & 1) * 64;
    const int lr = lane & 15, lg = lane >> 4;
    const int brow = lane >> 2, bseg = lane & 3;
    f32x4 acc[4][4] = {};
    for (int kk = 0; kk < 1024; kk += 32) {
        #pragma unroll
        for (int j = 0; j < 2; ++j) {
            int chunk = wv * 2 + j;                  // 16 rows x 32 cols per 1 KiB chunk
            int trow = chunk * 16 + brow;
            int sseg = bseg ^ ((trow >> 1) & 3);     // pre-swizzled global source segment
            const unsigned short* ga = A + (size_t)(m0 + trow) * 1024 + kk + sseg * 8;
            __builtin_amdgcn_global_load_lds((gv_t*)ga, (lv_t*)&As[chunk * 512], 16, 0, 0);
            const unsigned short* gb = Wb + (size_t)(n0 + trow) * 1024 + kk + sseg * 8;
            __builtin_amdgcn_global_load_lds((gv_t*)gb, (lv_t*)&Bs[chunk * 512], 16, 0, 0);
        }
        __syncthreads();
        bf16x8 af[4], bfv[4];
        #pragma unroll
        for (int m = 0; m < 4; ++m) {
            int R = wr + m * 16 + lr;
            int seg = lg ^ ((R >> 1) & 3);           // matching read-side swizzle (2-way banks)
            af[m] = *reinterpret_cast<const bf16x8*>(&As[R * 32 + seg * 8]);
        }
        #pragma unroll
        for (int n = 0; n < 4; ++n) {
            int R = wc + n * 16 + lr;
            int seg = lg ^ ((R >> 1) & 3);
            bfv[n] = *reinterpret_cast<const bf16x8*>(&Bs[R * 32 + seg * 8]);
        }
        #pragma unroll
        for (int m = 0; m < 4; ++m)
            #pragma unroll
            for (int n = 0; n < 4; ++n)
                acc[m][n] = __builtin_amdgcn_mfma_f32_16x16x32_bf16(af[m], bfv[n], acc[m][n], 0, 0, 0);
        __syncthreads();
    }
    #pragma unroll
    for (int m = 0; m < 4; ++m)
        #pragma unroll
        for (int n = 0; n < 4; ++n)
            #pragma unroll
            for (int r = 0; r < 4; ++r) {
                int grow = m0 + wr + m * 16 + lg * 4 + r;
                int gcol = n0 + wc + n * 16 + lr;
                if (OUT_BF16) {
                    unsigned short bv = f2bf(acc[m][n][r]);
                    unsigned ov = __shfl_xor((unsigned)bv, 1);
                    if (!(lane & 1)) {
                        unsigned short* out = (unsigned short*)outp;
                        *reinterpret_cast<unsigned*>(out + (size_t)grow * 1024 + gcol) =
                            (unsigned)bv | (ov << 16);
                    }
                } else {
                    float v = acc[m][n][r];
                    float o = __shfl_xor(v, 1);
                    if (!(lane & 1)) {
                        float* out = (float*)outp;
                        float2 pv; pv.x = v; pv.y = o;
                        *reinterpret_cast<float2*>(out + (size_t)grow * 1024 + gcol) = pv;
                    }
                }
            }
}

// ---------------- K/V projection: A fp32 [M][1024] @ W fp32 [1024][1024]^T -> bf16 ----------------
__global__ __launch_bounds__(256)
void k_gemm_kv(const float* __restrict__ A, const float* __restrict__ W0,
               const float* __restrict__ W1, unsigned short* __restrict__ o0,
               unsigned short* __restrict__ o1, int M) {
    const float* W = blockIdx.z ? W1 : W0;
    unsigned short* out = blockIdx.z ? o1 : o0;
    __shared__ unsigned short As[128 * 32];
    __shared__ unsigned short Bs[128 * 32];
    const int tid = threadIdx.x, lane = tid & 63, wv = tid >> 6;
    const int m0 = blockIdx.x * 128, n0 = blockIdx.y * 128;
    const int wr = (wv >> 1) * 64, wc = (wv & 1) * 64;
    const int lr = lane & 15, lk = (lane >> 4) * 8, lg = lane >> 4;
    f32x4 acc[4][4] = {};
    for (int kk = 0; kk < 1024; kk += 32) {
        #pragma unroll
        for (int it = 0; it < 4; ++it) {
            int li = it * 256 + tid;
            int row = li >> 3, c4 = (li & 7) * 4;
            int gr = m0 + row;
            float4 v = make_float4(0.f, 0.f, 0.f, 0.f);
            if (gr < M) v = *reinterpret_cast<const float4*>(A + (size_t)gr * 1024 + kk + c4);
            u16x4 o = { f2bf(v.x), f2bf(v.y), f2bf(v.z), f2bf(v.w) };
            *reinterpret_cast<u16x4*>(&As[row * 32 + c4]) = o;
        }
        #pragma unroll
        for (int it = 0; it < 4; ++it) {
            int li = it * 256 + tid;
            int row = li >> 3, c4 = (li & 7) * 4;
            float4 v = *reinterpret_cast<const float4*>(W + (size_t)(n0 + row) * 1024 + kk + c4);
            u16x4 o = { f2bf(v.x), f2bf(v.y), f2bf(v.z), f2bf(v.w) };
            *reinterpret_cast<u16x4*>(&Bs[row * 32 + c4]) = o;
        }
        __syncthreads();
        bf16x8 af[4], bfv[4];
        #pragma unroll
        for (int m = 0; m < 4; ++m)
            af[m] = *reinterpret_cast<const bf16x8*>(&As[(wr + m * 16 + lr) * 32 + lk]);
        #pragma unroll
        for (int n = 0; n < 4; ++n)
            bfv[n] = *reinterpret_cast<const bf16x8*>(&Bs[(wc + n * 16 + lr) * 32 + lk]);
        #pragma unroll
        for (int m = 0; m < 4; ++m)
            #pragma unroll
            for (int n = 0; n < 4; ++n)
                acc[m][n] = __builtin_amdgcn_mfma_f32_16x16x32_bf16(af[m], bfv[n], acc[m][n], 0, 0, 0);
        __syncthreads();
    }
    #pragma unroll
    for (int m = 0; m < 4; ++m)
        #pragma unroll
        for (int n = 0; n < 4; ++n)
            #pragma unroll
            for (int r = 0; r < 4; ++r) {
                int grow = m0 + wr + m * 16 + lg * 4 + r;
                if (grow < M) {
                    int gcol = n0 + wc + n * 16 + lr;
                    out[(size_t)grow * 1024 + gcol] = f2bf(acc[m][n][r]);
                }
            }
}

// ---------------- attention v2: 128 q-rows x 1 head per block; direct global frags; 1 barrier ----
__global__ __launch_bounds__(256)
void k_attn2(unsigned short* __restrict__ q,        // [32768][1024] bf16, attn written in-place
             const unsigned short* __restrict__ kb, // [308][1024]
             const unsigned short* __restrict__ vb) {
    constexpr int VP = 104, PP = 104;               // 2-way-bank strides, 16B-aligned rows
    __shared__ unsigned short vt_s[64 * VP];        // 13312 B  V^T tile
    __shared__ unsigned short p_s[128 * PP];        // 26624 B  P (wave-private rows)
    const int tid = threadIdx.x, lane = tid & 63, wv = tid >> 6;
    const int m0 = blockIdx.x * 128;
    const int h = blockIdx.y, b = blockIdx.z;
    const size_t qbase = ((size_t)b * TVn + m0) * Cn + h * 64;
    const size_t kvbase = (size_t)b * TTn * Cn + h * 64;
    const int lr = lane & 15, lg = lane >> 4;

    // stage V^T (coalesced global read, scatter LDS write); cols t>=77 zeroed
    for (int li = tid; li < 80 * 64; li += 256) {
        int t = li >> 6, d = li & 63;
        unsigned short v = 0;
        if (t < 77) v = vb[kvbase + (size_t)t * Cn + d];
        vt_s[d * VP + t] = v;
    }
    for (int li = tid; li < 64 * 16; li += 256) {   // zero cols 80..95 (PV k-window is 0..95)
        int d = li >> 4, t = 80 + (li & 15);
        vt_s[d * VP + t] = 0;
    }

    // QK^T: A/B fragments straight from global (q block-private; K tiny + L2-hot)
    f32x4 sc[2][5] = {};
    #pragma unroll
    for (int ks = 0; ks < 2; ++ks) {
        bf16x8 qa[2], kf[5];
        #pragma unroll
        for (int mf = 0; mf < 2; ++mf)
            qa[mf] = *reinterpret_cast<const bf16x8*>(
                q + qbase + (size_t)(wv * 32 + mf * 16 + lr) * Cn + ks * 32 + lg * 8);
        #pragma unroll
        for (int nf = 0; nf < 5; ++nf) {
            int t = nf * 16 + lr; if (t > 76) t = 76;   // clamp; masked below
            kf[nf] = *reinterpret_cast<const bf16x8*>(
                kb + kvbase + (size_t)t * Cn + ks * 32 + lg * 8);
        }
        #pragma unroll
        for (int mf = 0; mf < 2; ++mf)
            #pragma unroll
            for (int nf = 0; nf < 5; ++nf)
                sc[mf][nf] = __builtin_amdgcn_mfma_f32_16x16x32_bf16(qa[mf], kf[nf], sc[mf][nf], 0, 0, 0);
    }

    // softmax over 77 keys (C-layout: row=(lane>>4)*4+r, col t = nf*16+(lane&15))
    float pr[2][5][4];
    float rs[2][4];
    #pragma unroll
    for (int mf = 0; mf < 2; ++mf) {
        #pragma unroll
        for (int r = 0; r < 4; ++r) {
            float mx = -1e30f;
            #pragma unroll
            for (int nf = 0; nf < 5; ++nf) {
                float s = sc[mf][nf][r];
                if (nf * 16 + lr >= 77) s = -1e30f;
                pr[mf][nf][r] = s;
                mx = fmaxf(mx, s);
            }
            #pragma unroll
            for (int x = 1; x < 16; x <<= 1) mx = fmaxf(mx, __shfl_xor(mx, x));
            float sum = 0.f;
            #pragma unroll
            for (int nf = 0; nf < 5; ++nf) {
                float p = (pr[mf][nf][r] > -1e29f) ? __expf((pr[mf][nf][r] - mx) * 0.125f) : 0.f;
                pr[mf][nf][r] = p;
                sum += p;
            }
            #pragma unroll
            for (int x = 1; x < 16; x <<= 1) sum += __shfl_xor(sum, x);
            rs[mf][r] = 1.f / sum;
        }
    }

    // P -> LDS (each wave writes only its own 32 rows)
    for (int li = lane; li < 512; li += 64) {       // zero own rows, cols 80..95
        int rr = wv * 32 + (li >> 4);
        p_s[rr * PP + 80 + (li & 15)] = 0;
    }
    #pragma unroll
    for (int mf = 0; mf < 2; ++mf)
        #pragma unroll
        for (int r = 0; r < 4; ++r)
            #pragma unroll
            for (int nf = 0; nf < 5; ++nf)
                p_s[(wv * 32 + mf * 16 + lg * 4 + r) * PP + nf * 16 + lr] = f2bf(pr[mf][nf][r]);

    __syncthreads();  // the ONLY barrier: vt_s staging visible; own-row p_s needs none

    // PV
    f32x4 ovv[2][4] = {};
    #pragma unroll
    for (int ks = 0; ks < 3; ++ks) {
        bf16x8 pa[2], vf[4];
        #pragma unroll
        for (int mf = 0; mf < 2; ++mf)
            pa[mf] = *reinterpret_cast<const bf16x8*>(
                &p_s[(wv * 32 + mf * 16 + lr) * PP + ks * 32 + lg * 8]);
        #pragma unroll
        for (int nf = 0; nf < 4; ++nf)
            vf[nf] = *reinterpret_cast<const bf16x8*>(
                &vt_s[(nf * 16 + lr) * VP + ks * 32 + lg * 8]);
        #pragma unroll
        for (int mf = 0; mf < 2; ++mf)
            #pragma unroll
            for (int nf = 0; nf < 4; ++nf)
                ovv[mf][nf] = __builtin_amdgcn_mfma_f32_16x16x32_bf16(pa[mf], vf[nf], ovv[mf][nf], 0, 0, 0);
    }
    #pragma unroll
    for (int mf = 0; mf < 2; ++mf)
        #pragma unroll
        for (int nf = 0; nf < 4; ++nf)
            #pragma unroll
            for (int r = 0; r < 4; ++r) {
                float v = ovv[mf][nf][r] * rs[mf][r];
                unsigned short bv = f2bf(v);
                unsigned o = __shfl_xor((unsigned)bv, 1);
                if (!(lane & 1)) {
                    int row = m0 + wv * 32 + mf * 16 + lg * 4 + r;
                    int col = h * 64 + nf * 16 + lr;
                    *reinterpret_cast<unsigned*>(q + ((size_t)b * TVn + row) * Cn + col) =
                        (unsigned)bv | (o << 16);
                }
            }
}

extern "C" void kernel_launch(void* const* d_in, const int* in_sizes, int n_in,
                              void* d_out, int out_size, void* d_ws, size_t ws_size,
                              hipStream_t stream) {
    const float* video = (const float*)d_in[0];
    const float* text  = (const float*)d_in[1];
    const float* Wq = (const float*)d_in[2];
    const float* Wk = (const float*)d_in[3];
    const float* Wv = (const float*)d_in[4];
    const float* Wo = (const float*)d_in[5];
    float* out = (float*)d_out;

    char* ws = (char*)d_ws;
    unsigned short* wq_b = (unsigned short*)(ws);                    // 2 MiB
    unsigned short* wo_b = (unsigned short*)(ws + (2u << 20));       // 2 MiB
    unsigned short* kbuf = (unsigned short*)(ws + (4u << 20));       // 616 KiB
    unsigned short* vbuf = (unsigned short*)(ws + (5u << 20));       // 616 KiB
    unsigned short* qbuf = (unsigned short*)(ws + (6u << 20));       // 64 MiB (q, then attn in-place)
    unsigned short* vid_b = (unsigned short*)(ws + (70u << 20));     // 64 MiB video bf16

    k_cvt8<<<512, 256, 0, stream>>>(Wq, wq_b, 131072);
    k_cvt8<<<512, 256, 0, stream>>>(Wo, wo_b, 131072);

    dim3 gkv(3, 8, 2);  // ceil(308/128) x 1024/128 x {K,V}
    k_gemm_kv<<<gkv, 256, 0, stream>>>(text, Wk, Wv, kbuf, vbuf, Bn * TTn);

    k_cvt8<<<16384, 256, 0, stream>>>(video, vid_b, 4194304);

    k_gemm_bb<1><<<2048, 256, 0, stream>>>(vid_b, wq_b, (void*)qbuf);

    dim3 ga(TVn / 128, Hn, Bn);  // 64 x 16 x 4
    k_attn2<<<ga, 256, 0, stream>>>(qbuf, kbuf, vbuf);

    k_gemm_bb<0><<<2048, 256, 0, stream>>>(qbuf, wo_b, (void*)out);
}